// Round 5
// baseline (111.620 us; speedup 1.0000x reference)
//
#include <hip/hip_runtime.h>

// RoIAlign forward (SR=2, aligned). feat [4,256,100,100] f32, rois [512,5], out [512,256,7,7].
// BARRIER-FREE design: each wave autonomously processes one (roi, 2-channel)
// item in a private LDS region (patch 2x25x28 f32 + 28-entry geometry table).
// No __syncthreads anywhere — only intra-wave vmcnt/lgkmcnt waits — so the
// CU overlaps staging latency and compute across 24+ independent waves.

#define NROI   512
#define FEAT_C 256
#define FEAT_H 100
#define FEAT_W 100
#define HW     10000
#define NBINS  49
#define PROWS  25                    // floor-span <= 23, +2 tap rows
#define PSTR   28                    // 3 (align-down) + 23 + 2, multiple of 4
#define CSTR   (PSTR * PROWS)        // 700 dwords per channel
#define WLDS   (2 * CSTR + 56)       // + 28 int2 geometry entries = 1456 dwords

typedef float f32x2 __attribute__((ext_vector_type(2)));

__global__ __launch_bounds__(256, 6) void roialign_fwd(
    const float* __restrict__ feat,
    const float* __restrict__ rois,
    float* __restrict__ out)
{
    __shared__ __align__(16) float s_lds[4 * WLDS];   // 23296 B

    const int tid  = threadIdx.x;
    const int lane = tid & 63;
    const int w    = __builtin_amdgcn_readfirstlane(tid >> 6);  // wave id (SGPR)
    const int W    = blockIdx.x * 4 + w;              // wave-item id
    const int k    = W >> 7;                          // roi
    const int cg   = W & 127;                         // 2-channel group

    float* wp  = s_lds + w * WLDS;                    // wave-private patch
    int2*  tbl = (int2*)(wp + 2 * CSTR);              // entries 0-13: y, 14-27: x

    // ROI row (wave-uniform k -> scalar loads).
    const float* r = rois + k * 5;
    const float r0 = r[0], r1 = r[1], r2 = r[2], r3 = r[3], r4 = r[4];
    const int   b  = (int)r0;

    // ---- Geometry: all lanes compute (lanes >=28 compute dummy t=0) ----
    // EXACT same arithmetic as the verified round-2..4 kernels.
    const int  t   = lane < 28 ? lane : 0;
    const bool isy = t < 14;
    const int  u   = isy ? t : t - 14;
    float s   = (isy ? r2 : r1) * 0.25f - 0.5f;
    float e   = (isy ? r4 : r3) * 0.25f - 0.5f;
    float bsz = (e - s) * (1.0f / 7.0f);
    float v   = s + bsz * ((float)(u >> 1) + ((float)(u & 1) + 0.5f) * 0.5f);
    v = fmaxf(v, 0.0f);
    int lo = (int)v;                                  // v>=0: trunc == floor
    if (lo > FEAT_H - 1) lo = FEAT_H - 1;             // H == W == 100
    float fr = v - (float)lo;

    // Wave-uniform bounds via readlane (lane0=y first, 13=y last, 14=x first, 27=x last).
    const int y0  = __builtin_amdgcn_readlane(lo, 0);
    const int yM  = __builtin_amdgcn_readlane(lo, 13);
    const int x0  = __builtin_amdgcn_readlane(lo, 14);
    const int xM  = __builtin_amdgcn_readlane(lo, 27);
    const int ax0   = x0 & ~3;                        // 16B-aligned x origin
    const int rows  = yM - y0 + 2;                    // <= 25
    const int aspan = xM - ax0 + 2;                   // <= 28

    if (lane < 28) {
        if (!isy && lo >= FEAT_W - 1) fr = 0.0f;      // x-border: xh==xl -> kill weight
        int off = isy ? (lo - y0) * PSTR : (lo - ax0);
        tbl[lane] = make_int2(off, __float_as_int(fr));
    }

    // ---- Stage patch: lane -> (row = lane/7, quad = lane%7), 3 row-blocks x 2 ch ----
    const float* fb  = feat + (size_t)(b * FEAT_C + cg * 2) * HW;
    const int row = (lane * 9363) >> 16;              // lane/7, exact for lane<64
    const int q   = lane - row * 7;
    int col = ax0 + q * 4;
    if (col > FEAT_W - 4) col = FEAT_W - 4;           // clamped quads feed zero-weight cells
    const bool qok = (q * 4) < aspan;
    #pragma unroll
    for (int c = 0; c < 2; c++) {
        #pragma unroll
        for (int rb = 0; rb < 3; rb++) {
            int py = rb * 9 + row;                    // rows 0-8 / 9-17 / 18-26
            if (qok && py < rows) {
                int sy = y0 + py;
                if (sy > FEAT_H - 1) sy = FEAT_H - 1; // bottom-row duplication
                const float4* g = (const float4*)(fb + c * HW + sy * FEAT_W + col);
                *(float4*)(wp + c * CSTR + py * PSTR + q * 4) = *g;
            }
        }
    }

    __builtin_amdgcn_wave_barrier();                  // scheduling fence (no HW cost)

    // ---- Compute: lanes 0-48, one bin x 2 channels (packed f32) ----
    if (lane < NBINS) {
        const int ph = (lane * 37) >> 8;              // lane/7, exact for lane<49
        const int pw = lane - ph * 7;

        const int4 yg = *(const int4*)(tbl + 2 * ph);
        const int4 xg = *(const int4*)(tbl + 14 + 2 * pw);
        const float* pA = wp;                         // channel 2cg
        const float* pB = wp + CSTR;                  // channel 2cg+1

        const float ly0 = __int_as_float(yg.y), hy0 = 1.0f - ly0;
        const float ly1 = __int_as_float(yg.w), hy1 = 1.0f - ly1;
        const float lx0 = __int_as_float(xg.y), hx0 = 1.0f - lx0;
        const float lx1 = __int_as_float(xg.w), hx1 = 1.0f - lx1;

        f32x2 acc = {0.0f, 0.0f};
        auto quad = [&](int ro, float hy, float ly, int xo, float hx, float lx) {
            const float* a = pA + ro + xo;
            const float* p = pB + ro + xo;
            f32x2 vL0 = {a[0],        p[0]};          // (0,1)/(28,29) dword offsets
            f32x2 vL1 = {a[1],        p[1]};          //  -> ds_read2_b32 pairs
            f32x2 vH0 = {a[PSTR],     p[PSTR]};
            f32x2 vH1 = {a[PSTR + 1], p[PSTR + 1]};
            f32x2 tt = vL0 * hx + vL1 * lx;
            f32x2 uu = vH0 * hx + vH1 * lx;
            acc += tt * hy + uu * ly;
        };
        quad(yg.x, hy0, ly0, xg.x, hx0, lx0);
        quad(yg.x, hy0, ly0, xg.z, hx1, lx1);
        quad(yg.z, hy1, ly1, xg.x, hx0, lx0);
        quad(yg.z, hy1, ly1, xg.z, hx1, lx1);
        acc *= 0.25f;                                 // / (SR*SR)

        float* ob = out + ((size_t)k * FEAT_C + cg * 2) * NBINS + lane;
        ob[0]     = acc.x;
        ob[NBINS] = acc.y;
    }
}

extern "C" void kernel_launch(void* const* d_in, const int* in_sizes, int n_in,
                              void* d_out, int out_size, void* d_ws, size_t ws_size,
                              hipStream_t stream) {
    const float* feat = (const float*)d_in[0];
    const float* rois = (const float*)d_in[1];
    float*       outp = (float*)d_out;
    // 512 rois x 128 two-channel groups = 65536 wave-items, 4 waves/block.
    roialign_fwd<<<dim3(NROI * 128 / 4), dim3(256), 0, stream>>>(feat, rois, outp);
}

// Round 6
// 105.167 us; speedup vs baseline: 1.0614x; 1.0614x over previous
//
#include <hip/hip_runtime.h>

// RoIAlign forward (SR=2, aligned). feat [4,256,100,100] f32, rois [512,5], out [512,256,7,7].
// SEPARABLE scheme: staging threads y-interpolate in registers (row[ys][x] =
// hy*feat[yl,x] + ly*feat[yh,x]) and write 14 channel-pair-interleaved sample
// rows to LDS (branch-free, float4 loads, b128 writes). Compute then needs
// only the x-interpolation: one ds_read2_b64 per sample per channel-pair.
// LDS 13.6 KB/block -> 8 blocks/CU (32 waves). ONE barrier.

#define FEAT_C 256
#define FEAT_H 100
#define FEAT_W 100
#define HW     10000
#define NROI   512
#define NBINS  49
#define CPB    8                      // channels per block = 4 interleaved pairs
#define GROUPS 32                     // FEAT_C / CPB
#define NPAIR  4
#define YS     14                     // y-sample rows
#define RSTR   60                     // row stride (dwords): 28 px * 2ch = 56, +4 pad (16B-mult)
#define PAIRSTR (YS * RSTR)           // 840 dwords per channel pair

typedef float f32x2 __attribute__((ext_vector_type(2)));

// Matches ref: v = max(v,0); l = floor(v) clamped at cap(=99); fr = v - l_clamped.
__device__ __forceinline__ void samp_geo(float s, float bsz, int idx, int sr_i,
                                         int& lo, float& fr) {
    float v = s + bsz * ((float)idx + ((float)sr_i + 0.5f) * 0.5f);
    v = fmaxf(v, 0.0f);
    int l = (int)v;                   // v>=0: trunc == floor == astype(int32)
    if (l > FEAT_H - 1) l = FEAT_H - 1;
    fr = v - (float)l;
    lo = l;
}

__global__ __launch_bounds__(256, 8) void roialign_fwd(
    const float* __restrict__ feat,
    const float* __restrict__ rois,
    float* __restrict__ out)
{
    __shared__ __align__(16) float s_rows[NPAIR * PAIRSTR];  // 13440 B
    __shared__ __align__(16) int2  s_xt[YS];                 // {(xl-ax0)*2, bits(lx')}

    const int bid = blockIdx.x;
    const int k   = bid >> 5;
    const int cg  = bid & (GROUPS - 1);
    const int tid = threadIdx.x;

    const float* r = rois + k * 5;    // k wave-uniform -> scalar loads
    const int   b  = (int)r[0];
    const float sw = r[1] * 0.25f - 0.5f;
    const float sh = r[2] * 0.25f - 0.5f;
    const float ew = r[3] * 0.25f - 0.5f;
    const float eh = r[4] * 0.25f - 0.5f;
    const float bh = (eh - sh) * (1.0f / 7.0f);
    const float bw = (ew - sw) * (1.0f / 7.0f);

    // x origin (bit-identical in every thread).
    int x0; float fd;
    samp_geo(sw, bw, 0, 0, x0, fd);
    const int ax0 = x0 & ~3;          // 16B-aligned -> clamped quads stay harmless

    // x-geometry table (lanes 0..13 of wave 0, before the single barrier).
    if (tid < YS) {
        int lo; float fr;
        samp_geo(sw, bw, tid >> 1, tid & 1, lo, fr);
        if (lo >= FEAT_W - 1) fr = 0.0f;          // border: xh==xl -> kill high-tap weight
        s_xt[tid] = make_int2((lo - ax0) * 2, __float_as_int(fr));
    }

    // ---- Staging with fused y-interp: tid<196 -> (half, ys=sid/7, q=sid%7) ----
    if (tid < 2 * 98) {
        const int half = tid >= 98;
        const int sid  = tid - 98 * half;
        const int ys   = (sid * 9363) >> 16;      // sid/7 (exact, sid<98)
        const int q    = sid - ys * 7;

        int yl; float fry;
        samp_geo(sh, bh, ys >> 1, ys & 1, yl, fry);
        int yh = yl + 1; if (yh > FEAT_H - 1) yh = FEAT_H - 1;
        const float hyw = 1.0f - fry, lyw = fry;

        int col = ax0 + q * 4;
        if (col > FEAT_W - 4) col = FEAT_W - 4;   // only fully-OOB quads clamp (4-aligned)

        const float* fb = feat + (size_t)(b * FEAT_C + cg * CPB) * HW
                        + yl * FEAT_W + col;
        const int dyh = (yh - yl) * FEAT_W;
        float* dbase = s_rows + ys * RSTR + q * 8;

        for (int p = 2 * half; p < 2 * half + 2; p++) {   // this thread's 2 pairs
            const float* c0 = fb + (2 * p) * HW;
            const float* c1 = c0 + HW;
            float4 L0 = *(const float4*)(c0);
            float4 H0 = *(const float4*)(c0 + dyh);
            float4 L1 = *(const float4*)(c1);
            float4 H1 = *(const float4*)(c1 + dyh);
            float4 r0, r1;                         // y-interpolated sample rows
            r0.x = L0.x * hyw + H0.x * lyw;  r0.y = L0.y * hyw + H0.y * lyw;
            r0.z = L0.z * hyw + H0.z * lyw;  r0.w = L0.w * hyw + H0.w * lyw;
            r1.x = L1.x * hyw + H1.x * lyw;  r1.y = L1.y * hyw + H1.y * lyw;
            r1.z = L1.z * hyw + H1.z * lyw;  r1.w = L1.w * hyw + H1.w * lyw;
            float* d = dbase + p * PAIRSTR;        // [pair][ys][x][2ch] interleave
            *(float4*)(d)     = make_float4(r0.x, r1.x, r0.y, r1.y);
            *(float4*)(d + 4) = make_float4(r0.z, r1.z, r0.w, r1.w);
        }
    }
    __syncthreads();

    // ---- Compute: tid<196 -> (pair cp, bin); x-interp only, 4 ds_read2_b64 ----
    if (tid < 4 * NBINS) {
        const int cp  = (tid * 335) >> 14;        // tid/49 (exact, tid<196)
        const int bin = tid - cp * NBINS;
        const int ph  = (bin * 37) >> 8;          // bin/7 (exact, bin<49)
        const int pw  = bin - ph * 7;

        const int4 xg = *(const int4*)(&s_xt[2 * pw]);   // {off0,lx0, off1,lx1}
        const float lx0 = __int_as_float(xg.y), hx0 = 1.0f - lx0;
        const float lx1 = __int_as_float(xg.w), hx1 = 1.0f - lx1;

        const float* P = s_rows + cp * PAIRSTR + (2 * ph) * RSTR;
        f32x2 acc = {0.0f, 0.0f};
        #pragma unroll
        for (int iy = 0; iy < 2; iy++) {
            const float* row = P + iy * RSTR;
            const f32x2* A = (const f32x2*)(row + xg.x);  // xl, xl+1 both ch:
            f32x2 a0 = A[0], a1 = A[1];                   //   one ds_read2_b64
            const f32x2* B = (const f32x2*)(row + xg.z);
            f32x2 b0 = B[0], b1 = B[1];
            acc += a0 * hx0 + a1 * lx0;                   // v_pk_fma_f32
            acc += b0 * hx1 + b1 * lx1;
        }
        acc *= 0.25f;                                     // / (SR*SR)

        float* ob = out + ((size_t)k * FEAT_C + cg * CPB + cp * 2) * NBINS + bin;
        ob[0]     = acc.x;
        ob[NBINS] = acc.y;
    }
}

extern "C" void kernel_launch(void* const* d_in, const int* in_sizes, int n_in,
                              void* d_out, int out_size, void* d_ws, size_t ws_size,
                              hipStream_t stream) {
    const float* feat = (const float*)d_in[0];
    const float* rois = (const float*)d_in[1];
    float*       outp = (float*)d_out;
    roialign_fwd<<<dim3(NROI * GROUPS), dim3(256), 0, stream>>>(feat, rois, outp);
}